// Round 1
// baseline (547.594 us; speedup 1.0000x reference)
//
#include <hip/hip_runtime.h>
#include <hip/hip_bf16.h>
#include <stdint.h>

typedef unsigned short u16;
typedef unsigned int u32;

#define T_TOK 8192
#define DIN   4096
#define DOUT  4096
#define NL    16
#define NR    16
#define KX    4096              // x part of extended-K
#define K2    4416              // 4096 + 256 (Z) + 64 (bias/onehot/pad), = 69*64

#define BM 128
#define BN 128
#define BK 64
#define NKT (K2 / BK)           // 69

typedef __attribute__((ext_vector_type(8))) __bf16 bf16x8;
typedef __attribute__((ext_vector_type(4))) float  f32x4;

__device__ __forceinline__ u32 bf16rne(float f) {
    u32 x = __float_as_uint(f);
    return (x + 0x7FFFu + ((x >> 16) & 1u)) >> 16;
}
__device__ __forceinline__ u32 pack2(float a, float b) {
    return bf16rne(a) | (bf16rne(b) << 16);
}
__device__ __forceinline__ float bf2f(u32 u) {     // u must be <= 0xFFFF
    return __uint_as_float(u << 16);
}
__device__ __forceinline__ void unpack8(uint4 v, float* f) {
    f[0] = bf2f(v.x & 0xFFFFu); f[1] = bf2f(v.x >> 16);
    f[2] = bf2f(v.y & 0xFFFFu); f[3] = bf2f(v.y >> 16);
    f[4] = bf2f(v.z & 0xFFFFu); f[5] = bf2f(v.z >> 16);
    f[6] = bf2f(v.w & 0xFFFFu); f[7] = bf2f(v.w >> 16);
}

// ---------------- pack kernels ----------------

// f32 [rows x 4096] -> bf16 into dst rows of stride K2 (cols 0..4095)
__global__ void pack_mat(const float* __restrict__ src, u16* __restrict__ dst, int rows) {
    const int total = rows * (DIN / 8);
    for (int i = blockIdx.x * blockDim.x + threadIdx.x; i < total;
         i += gridDim.x * blockDim.x) {
        int row = i >> 9;                 // DIN/8 = 512 chunks per row
        int c8  = (i & 511) << 3;
        const float4* s = (const float4*)(src + (size_t)row * DIN + c8);
        float4 f0 = s[0], f1 = s[1];
        uint4 u;
        u.x = pack2(f0.x, f0.y); u.y = pack2(f0.z, f0.w);
        u.z = pack2(f1.x, f1.y); u.w = pack2(f1.z, f1.w);
        *(uint4*)(dst + (size_t)row * K2 + c8) = u;
    }
}

// B' cols 4096..4415: [lora_b flat | base_bias | bias_stacked | zero-pad]
__global__ void pack_bextra(const float* __restrict__ lora_b,
                            const float* __restrict__ base_bias,
                            const float* __restrict__ bias_st,
                            u16* __restrict__ Bbf) {
    const int total = DOUT * 320;         // 320 extra cols per output row
    for (int i = blockIdx.x * blockDim.x + threadIdx.x; i < total;
         i += gridDim.x * blockDim.x) {
        int o = i / 320;
        int j = i - o * 320;
        float v = 0.f;
        if (j < 256) {                    // Z columns: Bflat[l*16+r][o] = lora_b[l][o][r]
            int l = j >> 4, r = j & 15;
            v = lora_b[((size_t)l * DOUT + o) * NR + r];
        } else if (j == 256) {
            v = base_bias[o];
        } else if (j < 273) {
            v = bias_st[(size_t)(j - 257) * DOUT + o];
        }
        Bbf[(size_t)o * K2 + KX + j] = (u16)bf16rne(v);
    }
}

// lora_a f32 -> bf16, contiguous [L][R][DIN]
__global__ void conv_la(const float* __restrict__ la, u16* __restrict__ dst) {
    const int total = NL * NR * DIN / 8;  // 131072
    for (int i = blockIdx.x * blockDim.x + threadIdx.x; i < total;
         i += gridDim.x * blockDim.x) {
        int c8 = i << 3;
        const float4* s = (const float4*)(la + c8);
        float4 f0 = s[0], f1 = s[1];
        uint4 u;
        u.x = pack2(f0.x, f0.y); u.y = pack2(f0.z, f0.w);
        u.z = pack2(f1.x, f1.y); u.w = pack2(f1.z, f1.w);
        *(uint4*)(dst + c8) = u;
    }
}

// ---------------- shrink: one wave per token ----------------
// Computes shrunk[t][r] = dot(x[t], lora_a[idx[t]][r]) from bf16 copies, and
// fills A' cols 4096..4415: Z block (onehot-masked shrunk), bias onehots, pad.
__global__ __launch_bounds__(256) void shrink_kernel(const int* __restrict__ idx,
                                                     const u16* __restrict__ Aabf,
                                                     u16* __restrict__ Abf) {
    int wid  = threadIdx.x >> 6;
    int lane = threadIdx.x & 63;
    int t = blockIdx.x * 4 + wid;
    int l = idx[t];

    u16* rowp = Abf + (size_t)t * K2;
    u32* z = (u32*)(rowp + KX);           // 160 dwords: 128 Z + 32 bias/onehot

    float acc[16];
#pragma unroll
    for (int r = 0; r < 16; ++r) acc[r] = 0.f;

    if (l >= 0) {
        const u16* xr = rowp;                                  // bf16 x row
        const u16* ab = Aabf + (size_t)l * (NR * DIN);
#pragma unroll
        for (int c = 0; c < 8; ++c) {
            uint4 xv = *(const uint4*)(xr + c * 512 + lane * 8);
            float xf[8];
            unpack8(xv, xf);
#pragma unroll
            for (int r = 0; r < 16; ++r) {
                uint4 av = *(const uint4*)(ab + r * DIN + c * 512 + lane * 8);
                float af[8];
                unpack8(av, af);
#pragma unroll
                for (int e = 0; e < 8; ++e) acc[r] = fmaf(xf[e], af[e], acc[r]);
            }
        }
        // butterfly reduce across the 64 lanes (all lanes end with totals)
#pragma unroll
        for (int s = 1; s < 64; s <<= 1) {
#pragma unroll
            for (int r = 0; r < 16; ++r) acc[r] += __shfl_xor(acc[r], s, 64);
        }
    }

    // zero Z region (cols 4096..4351) except the 8 dwords lane 0 will fill
#pragma unroll
    for (int q = 0; q < 2; ++q) {
        int j = lane + q * 64;
        bool isval = (l >= 0) && (j >= l * 8) && (j < l * 8 + 8);
        if (!isval) z[j] = 0u;
    }
    // bias/onehot region: cols 4352..4415 (32 dwords). col 4352 = 1.0 always
    // (base bias), col 4353+l = 1.0 if l>=0, rest 0.
    if (lane < 32) {
        int e0 = KX + 256 + 2 * lane;
        u32 v0 = (e0 == 4352 || (l >= 0 && e0 == 4353 + l)) ? 0x3F80u : 0u;
        int e1 = e0 + 1;
        u32 v1 = (e1 == 4352 || (l >= 0 && e1 == 4353 + l)) ? 0x3F80u : 0u;
        z[128 + lane] = v0 | (v1 << 16);
    }
    // lane 0 writes the 16 shrunk values (8 dwords), static register indexing
    if (l >= 0 && lane == 0) {
        u32* zp = z + l * 8;
#pragma unroll
        for (int j = 0; j < 8; ++j) zp[j] = pack2(acc[2 * j], acc[2 * j + 1]);
    }
}

// ---------------- main GEMM: C[8192x4096] = A'[8192xK2] * B'[4096xK2]^T ----------------
// m97 structure: 128x128 tile, BK=64, 256 threads (4 waves 2x2), linear LDS,
// global_load_lds width 16, 2-barrier K-loop, 16x16x32 bf16 MFMA.
__global__ __launch_bounds__(256) void gemm_kernel(const u16* __restrict__ A,
                                                   const u16* __restrict__ B,
                                                   float* __restrict__ C) {
    __shared__ u16 sA[BM * BK];
    __shared__ u16 sB[BN * BK];

    const int tid  = threadIdx.x;
    const int wid  = tid >> 6;
    const int lane = tid & 63;
    const int wr = wid >> 1, wc = wid & 1;

    // XCD-aware swizzle (grid = 2048, 2048 % 8 == 0 -> bijective)
    int wg  = blockIdx.x;
    int swz = (wg & 7) * 256 + (wg >> 3);
    int bn = swz & 31;          // 32 col-tiles
    int bm = swz >> 5;          // 64 row-tiles

    const u16* Ag = A + (size_t)bm * BM * K2;
    const u16* Bg = B + (size_t)bn * BN * K2;

    // staging geometry: issue j covers rows j*32..j*32+31; thread -> 8 elems
    const int sr = tid >> 3;            // 0..31
    const int sc = (tid & 7) << 3;      // 0..56 step 8

    f32x4 acc[4][4];
#pragma unroll
    for (int m = 0; m < 4; ++m)
#pragma unroll
        for (int n = 0; n < 4; ++n) {
            f32x4 zero = {0.f, 0.f, 0.f, 0.f};
            acc[m][n] = zero;
        }

    const int lrow = lane & 15;
    const int lk   = (lane >> 4) << 3;  // k-offset 0/8/16/24

    for (int kt = 0; kt < NKT; ++kt) {
        const u16* ga = Ag + (size_t)sr * K2 + kt * BK + sc;
        const u16* gb = Bg + (size_t)sr * K2 + kt * BK + sc;
#pragma unroll
        for (int j = 0; j < 4; ++j) {
            __builtin_amdgcn_global_load_lds(
                (const __attribute__((address_space(1))) u32*)(ga + (size_t)j * 32 * K2),
                (__attribute__((address_space(3))) u32*)(&sA[j * 2048 + tid * 8]),
                16, 0, 0);
        }
#pragma unroll
        for (int j = 0; j < 4; ++j) {
            __builtin_amdgcn_global_load_lds(
                (const __attribute__((address_space(1))) u32*)(gb + (size_t)j * 32 * K2),
                (__attribute__((address_space(3))) u32*)(&sB[j * 2048 + tid * 8]),
                16, 0, 0);
        }
        __syncthreads();   // drains vmcnt before compute

#pragma unroll
        for (int kk = 0; kk < BK; kk += 32) {
            bf16x8 av[4], bv[4];
#pragma unroll
            for (int m = 0; m < 4; ++m)
                av[m] = *(const bf16x8*)&sA[(wr * 64 + m * 16 + lrow) * BK + kk + lk];
#pragma unroll
            for (int n = 0; n < 4; ++n)
                bv[n] = *(const bf16x8*)&sB[(wc * 64 + n * 16 + lrow) * BK + kk + lk];
#pragma unroll
            for (int m = 0; m < 4; ++m)
#pragma unroll
                for (int n = 0; n < 4; ++n)
                    acc[m][n] = __builtin_amdgcn_mfma_f32_16x16x32_bf16(
                        av[m], bv[n], acc[m][n], 0, 0, 0);
        }
        __syncthreads();   // LDS safe to overwrite
    }

    // epilogue: C/D layout col = lane&15, row = (lane>>4)*4 + reg
    const int crow0 = bm * BM + wr * 64 + ((lane >> 4) << 2);
    const int ccol0 = bn * BN + wc * 64 + (lane & 15);
#pragma unroll
    for (int m = 0; m < 4; ++m) {
#pragma unroll
        for (int n = 0; n < 4; ++n) {
            int col = ccol0 + n * 16;
#pragma unroll
            for (int rg = 0; rg < 4; ++rg) {
                int row = crow0 + m * 16 + rg;
                C[(size_t)row * DOUT + col] = acc[m][n][rg];
            }
        }
    }
}

// ---------------- launch ----------------

extern "C" void kernel_launch(void* const* d_in, const int* in_sizes, int n_in,
                              void* d_out, int out_size, void* d_ws, size_t ws_size,
                              hipStream_t stream) {
    const float* x         = (const float*)d_in[0];
    const float* W         = (const float*)d_in[1];
    const float* base_bias = (const float*)d_in[2];
    const float* lora_a    = (const float*)d_in[3];
    const float* lora_b    = (const float*)d_in[4];
    const float* bias_st   = (const float*)d_in[5];
    const int*   indices   = (const int*)d_in[6];
    float* out = (float*)d_out;

    u16* Abf  = (u16*)d_ws;                         // [T_TOK][K2] bf16
    u16* Bbf  = Abf + (size_t)T_TOK * K2;           // [DOUT][K2] bf16
    u16* Aabf = Bbf + (size_t)DOUT * K2;            // [L][R][DIN] bf16

    pack_mat<<<4096, 256, 0, stream>>>(x, Abf, T_TOK);
    pack_mat<<<2048, 256, 0, stream>>>(W, Bbf, DOUT);
    pack_bextra<<<2048, 256, 0, stream>>>(lora_b, base_bias, bias_st, Bbf);
    conv_la<<<512, 256, 0, stream>>>(lora_a, Aabf);
    shrink_kernel<<<T_TOK / 4, 256, 0, stream>>>(indices, Aabf, Abf);
    gemm_kernel<<<2048, 256, 0, stream>>>(Abf, Bbf, out);
    (void)in_sizes; (void)n_in; (void)out_size; (void)ws_size;
}

// Round 2
// 369.445 us; speedup vs baseline: 1.4822x; 1.4822x over previous
//
#include <hip/hip_runtime.h>
#include <hip/hip_bf16.h>
#include <stdint.h>

typedef unsigned short u16;
typedef unsigned int u32;

#define T_TOK 8192
#define DIN   4096
#define DOUT  4096
#define NL    16
#define NR    16
#define KX    4096              // x part of extended-K
#define K2    4416              // 4096 + 256 (Z) + 64 (bias/onehot/pad) = 69*64
#define NKT   69                // K-tiles of 64
#define GITERS 34               // main-loop iterations (2 K-tiles each); K-tile 68 in tail

typedef __attribute__((ext_vector_type(8))) __bf16 bf16x8;
typedef __attribute__((ext_vector_type(4))) float  f32x4;

__device__ __forceinline__ u32 bf16rne(float f) {
    u32 x = __float_as_uint(f);
    return (x + 0x7FFFu + ((x >> 16) & 1u)) >> 16;
}
__device__ __forceinline__ u32 pack2(float a, float b) {
    return bf16rne(a) | (bf16rne(b) << 16);
}
__device__ __forceinline__ float bf2f(u32 u) {
    return __uint_as_float(u << 16);
}
__device__ __forceinline__ void unpack8(uint4 v, float* f) {
    f[0] = bf2f(v.x & 0xFFFFu); f[1] = bf2f(v.x >> 16);
    f[2] = bf2f(v.y & 0xFFFFu); f[3] = bf2f(v.y >> 16);
    f[4] = bf2f(v.z & 0xFFFFu); f[5] = bf2f(v.z >> 16);
    f[6] = bf2f(v.w & 0xFFFFu); f[7] = bf2f(v.w >> 16);
}

// ---------------- pack kernels (unchanged from round 1, verified) ----------------

__global__ void pack_mat(const float* __restrict__ src, u16* __restrict__ dst, int rows) {
    const int total = rows * (DIN / 8);
    for (int i = blockIdx.x * blockDim.x + threadIdx.x; i < total;
         i += gridDim.x * blockDim.x) {
        int row = i >> 9;
        int c8  = (i & 511) << 3;
        const float4* s = (const float4*)(src + (size_t)row * DIN + c8);
        float4 f0 = s[0], f1 = s[1];
        uint4 u;
        u.x = pack2(f0.x, f0.y); u.y = pack2(f0.z, f0.w);
        u.z = pack2(f1.x, f1.y); u.w = pack2(f1.z, f1.w);
        *(uint4*)(dst + (size_t)row * K2 + c8) = u;
    }
}

__global__ void pack_bextra(const float* __restrict__ lora_b,
                            const float* __restrict__ base_bias,
                            const float* __restrict__ bias_st,
                            u16* __restrict__ Bbf) {
    const int total = DOUT * 320;
    for (int i = blockIdx.x * blockDim.x + threadIdx.x; i < total;
         i += gridDim.x * blockDim.x) {
        int o = i / 320;
        int j = i - o * 320;
        float v = 0.f;
        if (j < 256) {
            int l = j >> 4, r = j & 15;
            v = lora_b[((size_t)l * DOUT + o) * NR + r];
        } else if (j == 256) {
            v = base_bias[o];
        } else if (j < 273) {
            v = bias_st[(size_t)(j - 257) * DOUT + o];
        }
        Bbf[(size_t)o * K2 + KX + j] = (u16)bf16rne(v);
    }
}

__global__ void conv_la(const float* __restrict__ la, u16* __restrict__ dst) {
    const int total = NL * NR * DIN / 8;
    for (int i = blockIdx.x * blockDim.x + threadIdx.x; i < total;
         i += gridDim.x * blockDim.x) {
        int c8 = i << 3;
        const float4* s = (const float4*)(la + c8);
        float4 f0 = s[0], f1 = s[1];
        uint4 u;
        u.x = pack2(f0.x, f0.y); u.y = pack2(f0.z, f0.w);
        u.z = pack2(f1.x, f1.y); u.w = pack2(f1.z, f1.w);
        *(uint4*)(dst + c8) = u;
    }
}

// ---------------- shrink (unchanged from round 1, verified) ----------------
__global__ __launch_bounds__(256) void shrink_kernel(const int* __restrict__ idx,
                                                     const u16* __restrict__ Aabf,
                                                     u16* __restrict__ Abf) {
    int wid  = threadIdx.x >> 6;
    int lane = threadIdx.x & 63;
    int t = blockIdx.x * 4 + wid;
    int l = idx[t];

    u16* rowp = Abf + (size_t)t * K2;
    u32* z = (u32*)(rowp + KX);

    float acc[16];
#pragma unroll
    for (int r = 0; r < 16; ++r) acc[r] = 0.f;

    if (l >= 0) {
        const u16* xr = rowp;
        const u16* ab = Aabf + (size_t)l * (NR * DIN);
#pragma unroll
        for (int c = 0; c < 8; ++c) {
            uint4 xv = *(const uint4*)(xr + c * 512 + lane * 8);
            float xf[8];
            unpack8(xv, xf);
#pragma unroll
            for (int r = 0; r < 16; ++r) {
                uint4 av = *(const uint4*)(ab + r * DIN + c * 512 + lane * 8);
                float af[8];
                unpack8(av, af);
#pragma unroll
                for (int e = 0; e < 8; ++e) acc[r] = fmaf(xf[e], af[e], acc[r]);
            }
        }
#pragma unroll
        for (int s = 1; s < 64; s <<= 1) {
#pragma unroll
            for (int r = 0; r < 16; ++r) acc[r] += __shfl_xor(acc[r], s, 64);
        }
    }

#pragma unroll
    for (int q = 0; q < 2; ++q) {
        int j = lane + q * 64;
        bool isval = (l >= 0) && (j >= l * 8) && (j < l * 8 + 8);
        if (!isval) z[j] = 0u;
    }
    if (lane < 32) {
        int e0 = KX + 256 + 2 * lane;
        u32 v0 = (e0 == 4352 || (l >= 0 && e0 == 4353 + l)) ? 0x3F80u : 0u;
        int e1 = e0 + 1;
        u32 v1 = (e1 == 4352 || (l >= 0 && e1 == 4353 + l)) ? 0x3F80u : 0u;
        z[128 + lane] = v0 | (v1 << 16);
    }
    if (l >= 0 && lane == 0) {
        u32* zp = z + l * 8;
#pragma unroll
        for (int j = 0; j < 8; ++j) zp[j] = pack2(acc[2 * j], acc[2 * j + 1]);
    }
}

// ---------------- main GEMM: 256x256 tile, 8-phase schedule (m201 template) ----------------
// 8 waves (2M x 4N), BK=64, 128 KiB LDS (2 dbuf x 4 segs x 128x64 bf16),
// counted vmcnt(6) at phases 4/8, two s_barrier per phase, setprio around MFMA,
// ((row&7)<<4) XOR swizzle applied source-side (global_load_lds) + on ds_read.

#define SBAR() __builtin_amdgcn_sched_barrier(0)
#define HWBAR() __builtin_amdgcn_s_barrier()
#define PHASE_BAR() do { SBAR(); HWBAR(); SBAR(); } while (0)
#define VMCNT6() asm volatile("s_waitcnt vmcnt(6)" ::: "memory")
#define VMCNT0() asm volatile("s_waitcnt vmcnt(0)" ::: "memory")

// stage one 128x64 half-tile (2 x global_load_lds dwordx4 per thread)
#define STAGE(ptr, h, buf, seg, kt)                                                   \
  do { if ((kt) < NKT) {                                                              \
    __builtin_amdgcn_global_load_lds(                                                 \
      (const __attribute__((address_space(1))) u32*)((ptr) + (size_t)((h)*128 + 0)*K2 + (size_t)(kt)*64),  \
      (__attribute__((address_space(3))) u32*)(lds16 + ((((buf)*4+(seg))<<13) + tid*8)), 16, 0, 0);        \
    __builtin_amdgcn_global_load_lds(                                                 \
      (const __attribute__((address_space(1))) u32*)((ptr) + (size_t)((h)*128 + 64)*K2 + (size_t)(kt)*64), \
      (__attribute__((address_space(3))) u32*)(lds16 + ((((buf)*4+(seg))<<13) + tid*8 + 4096)), 16, 0, 0); \
  } } while (0)

// read ALL 16 A-fragments of a K-tile (front-loaded: A segs fully read in the
// K-tile's first phase -> re-stageable one phase later)
#define RD_A(buf)                                                                     \
  { _Pragma("unroll") for (int m = 0; m < 8; ++m)                                     \
    _Pragma("unroll") for (int kk = 0; kk < 2; ++kk)                                  \
      a[m][kk] = *(const bf16x8*)(smem + (((buf)*4 + wr) << 14) + lrow*128 + m*2048 + kxb[kk]); }

// read one n-half (4 B-fragments)
#define RD_B(buf, nh, bf)                                                             \
  { _Pragma("unroll") for (int nn = 0; nn < 2; ++nn)                                  \
    _Pragma("unroll") for (int kk = 0; kk < 2; ++kk)                                  \
      bf[nn][kk] = *(const bf16x8*)(smem + (((buf)*4 + 2 + (wc>>1)) << 14)            \
          + ((wc&1)*64 + lrow)*128 + ((nh)*2+nn)*2048 + kxb[kk]); }

// one C-quadrant x K=64: 16 MFMA, setprio-wrapped (T5)
#define MMQ(mh, nh, bf)                                                               \
  { __builtin_amdgcn_s_setprio(1);                                                    \
    _Pragma("unroll") for (int mm = 0; mm < 4; ++mm)                                  \
    _Pragma("unroll") for (int nn = 0; nn < 2; ++nn)                                  \
    _Pragma("unroll") for (int kk = 0; kk < 2; ++kk)                                  \
      acc[(mh)*4+mm][(nh)*2+nn] = __builtin_amdgcn_mfma_f32_16x16x32_bf16(            \
          a[(mh)*4+mm][kk], bf[nn][kk], acc[(mh)*4+mm][(nh)*2+nn], 0, 0, 0);          \
    __builtin_amdgcn_s_setprio(0); }

__global__ __launch_bounds__(512, 2) void gemm_kernel(const u16* __restrict__ A,
                                                      const u16* __restrict__ B,
                                                      float* __restrict__ C) {
    __shared__ u16 lds16[65536];                 // 128 KiB
    const char* smem = (const char*)lds16;

    const int tid  = threadIdx.x;
    const int lane = tid & 63, wid = tid >> 6;
    const int wr = wid >> 2, wc = wid & 3;       // 2M x 4N wave grid
    const int lrow = lane & 15;
    const int klo  = (lane >> 4) << 4;           // k byte-offset 0/16/32/48
    const int sx   = (lrow & 7) << 4;            // XOR swizzle key
    const int kxb[2] = { klo ^ sx, (64 + klo) ^ sx };

    // XCD-aware swizzle: 512 blocks, 512 % 8 == 0 -> bijective
    const int wg  = blockIdx.x;
    const int swz = (wg & 7) * 64 + (wg >> 3);
    const int bm = swz >> 4;                     // 32 row-tiles
    const int bn = swz & 15;                     // 16 col-tiles

    // staging source (pre-swizzled chunk so linear LDS dest = swizzled layout)
    const int r0  = tid >> 3;                    // row within 64-row j-block
    const int sc4 = (tid & 7) ^ (r0 & 7);        // swizzled source 16B-chunk
    const u16* pA = A + (size_t)(bm * 256 + r0) * K2 + sc4 * 8;
    const u16* pB = B + (size_t)(bn * 256 + r0) * K2 + sc4 * 8;

    f32x4 acc[8][4];
#pragma unroll
    for (int m = 0; m < 8; ++m)
#pragma unroll
        for (int n = 0; n < 4; ++n) {
            f32x4 z = {0.f, 0.f, 0.f, 0.f};
            acc[m][n] = z;
        }
    bf16x8 a[8][2], bA[2][2], bB[2][2];

    // ---- prologue: K0 (4 halves) + K1 (A0,A1,B0); B1 of K1 staged at ph1 ----
    STAGE(pA, 0, 0, 0, 0); STAGE(pA, 1, 0, 1, 0);
    STAGE(pB, 0, 0, 2, 0); STAGE(pB, 1, 0, 3, 0);
    STAGE(pA, 0, 1, 0, 1); STAGE(pA, 1, 1, 1, 1);
    STAGE(pB, 0, 1, 2, 1);
    VMCNT6();                                    // K0 fully landed
    PHASE_BAR();

    for (int i = 0; i < GITERS; ++i) {
        const int k1  = 2 * i + 1;
        const int kn  = 2 * i + 2;
        const int kn1 = 2 * i + 3;
        // -- phase 1: compute K(2i) quadrant (mh0,nh0); stage K(2i+1).B1 --
        RD_A(0); RD_B(0, 0, bA);
        STAGE(pB, 1, 1, 3, k1);
        PHASE_BAR();
        MMQ(0, 0, bA);
        PHASE_BAR();
        // -- phase 2: (mh1,nh0); stage K(2i+2).A0 (A segs of buf0 fully read in ph1) --
        STAGE(pA, 0, 0, 0, kn);
        PHASE_BAR();
        MMQ(1, 0, bA);
        PHASE_BAR();
        // -- phase 3: (mh0,nh1); stage K(2i+2).A1 --
        RD_B(0, 1, bB);
        STAGE(pA, 1, 0, 1, kn);
        PHASE_BAR();
        MMQ(0, 1, bB);
        PHASE_BAR();
        // -- phase 4: (mh1,nh1); stage K(2i+2).B0; guard K(2i+1) landed --
        STAGE(pB, 0, 0, 2, kn);
        PHASE_BAR();
        MMQ(1, 1, bB);
        VMCNT6();
        PHASE_BAR();
        // -- phase 5: K(2i+1) (mh0,nh0); stage K(2i+2).B1 (buf0 B reads done ph3) --
        RD_A(1); RD_B(1, 0, bA);
        STAGE(pB, 1, 0, 3, kn);
        PHASE_BAR();
        MMQ(0, 0, bA);
        PHASE_BAR();
        // -- phase 6: (mh1,nh0); stage K(2i+3).A0 --
        STAGE(pA, 0, 1, 0, kn1);
        PHASE_BAR();
        MMQ(1, 0, bA);
        PHASE_BAR();
        // -- phase 7: (mh0,nh1); stage K(2i+3).A1 --
        RD_B(1, 1, bB);
        STAGE(pA, 1, 1, 1, kn1);
        PHASE_BAR();
        MMQ(0, 1, bB);
        PHASE_BAR();
        // -- phase 8: (mh1,nh1); stage K(2i+3).B0; guard K(2i+2) landed --
        STAGE(pB, 0, 1, 2, kn1);
        PHASE_BAR();
        MMQ(1, 1, bB);
        VMCNT6();
        PHASE_BAR();
    }

    // ---- tail: K-tile 68 (even -> buf0), staged during iter 33 ph2-5 ----
    VMCNT0();
    PHASE_BAR();
    RD_A(0); RD_B(0, 0, bA); RD_B(0, 1, bB);
    MMQ(0, 0, bA); MMQ(1, 0, bA); MMQ(0, 1, bB); MMQ(1, 1, bB);

    // ---- epilogue: C/D layout col = lane&15, row = (lane>>4)*4 + reg ----
    const int crow0 = bm * 256 + wr * 128 + ((lane >> 4) << 2);
    const int ccol0 = bn * 256 + wc * 64 + (lane & 15);
#pragma unroll
    for (int m = 0; m < 8; ++m)
#pragma unroll
        for (int n = 0; n < 4; ++n)
#pragma unroll
            for (int rg = 0; rg < 4; ++rg)
                C[(size_t)(crow0 + m * 16 + rg) * DOUT + ccol0 + n * 16] = acc[m][n][rg];
}

// ---------------- launch ----------------

extern "C" void kernel_launch(void* const* d_in, const int* in_sizes, int n_in,
                              void* d_out, int out_size, void* d_ws, size_t ws_size,
                              hipStream_t stream) {
    const float* x         = (const float*)d_in[0];
    const float* W         = (const float*)d_in[1];
    const float* base_bias = (const float*)d_in[2];
    const float* lora_a    = (const float*)d_in[3];
    const float* lora_b    = (const float*)d_in[4];
    const float* bias_st   = (const float*)d_in[5];
    const int*   indices   = (const int*)d_in[6];
    float* out = (float*)d_out;

    u16* Abf  = (u16*)d_ws;                         // [T_TOK][K2] bf16
    u16* Bbf  = Abf + (size_t)T_TOK * K2;           // [DOUT][K2] bf16
    u16* Aabf = Bbf + (size_t)DOUT * K2;            // [L][R][DIN] bf16

    pack_mat<<<4096, 256, 0, stream>>>(x, Abf, T_TOK);
    pack_mat<<<2048, 256, 0, stream>>>(W, Bbf, DOUT);
    pack_bextra<<<2048, 256, 0, stream>>>(lora_b, base_bias, bias_st, Bbf);
    conv_la<<<512, 256, 0, stream>>>(lora_a, Aabf);
    shrink_kernel<<<T_TOK / 4, 256, 0, stream>>>(indices, Aabf, Abf);
    gemm_kernel<<<512, 512, 0, stream>>>(Abf, Bbf, out);
    (void)in_sizes; (void)n_in; (void)out_size; (void)ws_size;
}

// Round 3
// 342.511 us; speedup vs baseline: 1.5988x; 1.0786x over previous
//
#include <hip/hip_runtime.h>
#include <hip/hip_bf16.h>
#include <stdint.h>

typedef unsigned short u16;
typedef unsigned int u32;

#define T_TOK 8192
#define DIN   4096
#define DOUT  4096
#define NL    16
#define NR    16
#define KX    4096              // x part of extended-K
#define K2    4416              // 4096 + 256 (Z) + 64 (bias/onehot/pad) = 69*64
#define NKT   69                // K-tiles of 64
#define GITERS 34               // main-loop iterations (2 K-tiles each); K-tile 68 in tail

typedef __attribute__((ext_vector_type(8))) __bf16 bf16x8;
typedef __attribute__((ext_vector_type(4))) float  f32x4;

__device__ __forceinline__ u32 bf16rne(float f) {
    u32 x = __float_as_uint(f);
    return (x + 0x7FFFu + ((x >> 16) & 1u)) >> 16;
}
__device__ __forceinline__ u32 pack2(float a, float b) {
    return bf16rne(a) | (bf16rne(b) << 16);
}

// ---------------- pack: x -> A' cols 0..4095, W -> B' cols 0..4095 ----------------
__global__ void pack_mats(const float* __restrict__ x, const float* __restrict__ W,
                          u16* __restrict__ Abf, u16* __restrict__ Bbf) {
    const int total = (T_TOK + DOUT) * (DIN / 8);
    for (int i = blockIdx.x * blockDim.x + threadIdx.x; i < total;
         i += gridDim.x * blockDim.x) {
        int row = i >> 9;
        int c8  = (i & 511) << 3;
        const float* src;
        u16* dst;
        if (row < T_TOK) { src = x + (size_t)row * DIN; dst = Abf + (size_t)row * K2; }
        else { src = W + (size_t)(row - T_TOK) * DIN; dst = Bbf + (size_t)(row - T_TOK) * K2; }
        const float4* s = (const float4*)(src + c8);
        float4 f0 = s[0], f1 = s[1];
        uint4 u;
        u.x = pack2(f0.x, f0.y); u.y = pack2(f0.z, f0.w);
        u.z = pack2(f1.x, f1.y); u.w = pack2(f1.z, f1.w);
        *(uint4*)(dst + c8) = u;
    }
}

// ---------------- pack_small: B' extra cols + lora_a -> bf16 ----------------
#define NBEX (DOUT * 320)
__global__ void pack_small(const float* __restrict__ lora_b,
                           const float* __restrict__ base_bias,
                           const float* __restrict__ bias_st,
                           const float* __restrict__ la,
                           u16* __restrict__ Bbf, u16* __restrict__ Aabf) {
    const int total = NBEX + NL * NR * DIN / 8;
    for (int i = blockIdx.x * blockDim.x + threadIdx.x; i < total;
         i += gridDim.x * blockDim.x) {
        if (i < NBEX) {
            int o = i / 320;
            int j = i - o * 320;
            float v = 0.f;
            if (j < 256) {
                int l = j >> 4, r = j & 15;
                v = lora_b[((size_t)l * DOUT + o) * NR + r];
            } else if (j == 256) {
                v = base_bias[o];
            } else if (j < 273) {
                v = bias_st[(size_t)(j - 257) * DOUT + o];
            }
            Bbf[(size_t)o * K2 + KX + j] = (u16)bf16rne(v);
        } else {
            int c8 = (i - NBEX) << 3;
            const float4* s = (const float4*)(la + c8);
            float4 f0 = s[0], f1 = s[1];
            uint4 u;
            u.x = pack2(f0.x, f0.y); u.y = pack2(f0.z, f0.w);
            u.z = pack2(f1.x, f1.y); u.w = pack2(f1.z, f1.w);
            *(uint4*)(Aabf + c8) = u;
        }
    }
}

// ---------------- zfill: Zfull = x_bf16 @ lora_a^T via MFMA, masked write ----------------
// grid 256 = 128 token-groups x 2 lr-halves; 512 threads = 8 waves (2M x 4N);
// per wave 32x32 output. Counted-vmcnt double-buffered staging.
__global__ __launch_bounds__(512) void zfill_kernel(const u16* __restrict__ Axr,
                                                    const u16* __restrict__ La,
                                                    const int* __restrict__ idx,
                                                    u16* __restrict__ Abf) {
    __shared__ u16 sX[2][64 * 64];        // 8KB each
    __shared__ u16 sL[2][128 * 64];       // 16KB each
    const int tid  = threadIdx.x;
    const int lane = tid & 63, wid = tid >> 6;
    const int wr = wid >> 2, wc = wid & 3;
    const int lrow = lane & 15;
    const int klo  = (lane >> 4) << 4;
    const int sxr  = (lrow & 7) << 4;
    const int kxb[2] = { klo ^ sxr, (64 + klo) ^ sxr };

    const int bt = blockIdx.x >> 1;       // token group (64 tokens)
    const int nh = blockIdx.x & 1;        // lr half (128 cols)

    const int r0 = tid >> 3;              // 0..63
    const int c4 = (tid & 7) ^ (r0 & 7);  // pre-swizzled source chunk
    const u16* pX = Axr + (size_t)(bt * 64 + r0) * K2 + c4 * 8;
    const u16* pL = La + (size_t)(nh * 128 + r0) * DIN + c4 * 8;       // rows 0..63 of half
    const u16* pL2 = La + (size_t)(nh * 128 + 64 + r0) * DIN + c4 * 8; // rows 64..127

    f32x4 acc[2][2];
#pragma unroll
    for (int m = 0; m < 2; ++m)
#pragma unroll
        for (int n = 0; n < 2; ++n) { f32x4 z = {0.f,0.f,0.f,0.f}; acc[m][n] = z; }

#define STAGEZ(buf, kt)                                                                \
  do {                                                                                 \
    __builtin_amdgcn_global_load_lds(                                                  \
      (const __attribute__((address_space(1))) u32*)(pX + (size_t)(kt) * 64),          \
      (__attribute__((address_space(3))) u32*)(&sX[buf][tid * 8]), 16, 0, 0);          \
    __builtin_amdgcn_global_load_lds(                                                  \
      (const __attribute__((address_space(1))) u32*)(pL + (size_t)(kt) * 64),          \
      (__attribute__((address_space(3))) u32*)(&sL[buf][tid * 8]), 16, 0, 0);          \
    __builtin_amdgcn_global_load_lds(                                                  \
      (const __attribute__((address_space(1))) u32*)(pL2 + (size_t)(kt) * 64),         \
      (__attribute__((address_space(3))) u32*)(&sL[buf][4096 + tid * 8]), 16, 0, 0);   \
  } while (0)

    STAGEZ(0, 0);
    for (int kt = 0; kt < 64; ++kt) {
        const int cur = kt & 1;
        if (kt < 63) {
            STAGEZ(cur ^ 1, kt + 1);
            asm volatile("s_waitcnt vmcnt(3)" ::: "memory");
        } else {
            asm volatile("s_waitcnt vmcnt(0)" ::: "memory");
        }
        __builtin_amdgcn_sched_barrier(0);
        __builtin_amdgcn_s_barrier();
        __builtin_amdgcn_sched_barrier(0);
        const char* sx = (const char*)sX[cur];
        const char* sl = (const char*)sL[cur];
        bf16x8 a[2][2], b[2][2];
#pragma unroll
        for (int m = 0; m < 2; ++m)
#pragma unroll
            for (int kk = 0; kk < 2; ++kk)
                a[m][kk] = *(const bf16x8*)(sx + (wr * 32 + m * 16 + lrow) * 128 + kxb[kk]);
#pragma unroll
        for (int n = 0; n < 2; ++n)
#pragma unroll
            for (int kk = 0; kk < 2; ++kk)
                b[n][kk] = *(const bf16x8*)(sl + (wc * 32 + n * 16 + lrow) * 128 + kxb[kk]);
#pragma unroll
        for (int m = 0; m < 2; ++m)
#pragma unroll
            for (int n = 0; n < 2; ++n)
#pragma unroll
                for (int kk = 0; kk < 2; ++kk)
                    acc[m][n] = __builtin_amdgcn_mfma_f32_16x16x32_bf16(
                        a[m][kk], b[n][kk], acc[m][n], 0, 0, 0);
        __builtin_amdgcn_sched_barrier(0);
        __builtin_amdgcn_s_barrier();
        __builtin_amdgcn_sched_barrier(0);
    }

    // masked Z write: Z[t][col] = (idx[t] == col>>4) ? Zfull : 0
#pragma unroll
    for (int m = 0; m < 2; ++m) {
#pragma unroll
        for (int rg = 0; rg < 4; ++rg) {
            int tl = wr * 32 + m * 16 + ((lane >> 4) << 2) + rg;
            int t  = bt * 64 + tl;
            int l  = idx[t];
#pragma unroll
            for (int n = 0; n < 2; ++n) {
                int col = nh * 128 + wc * 32 + n * 16 + (lane & 15);
                u16 v = ((col >> 4) == l) ? (u16)bf16rne(acc[m][n][rg]) : (u16)0;
                Abf[(size_t)t * K2 + KX + col] = v;
            }
        }
    }
    // bias/onehot cols 4352..4415 (only nh==0 blocks; 64 tokens x 8 chunks)
    if (nh == 0) {
        int tl = tid >> 3, c8 = (tid & 7) * 8;
        int t = bt * 64 + tl;
        int l = idx[t];
        u32 w[4];
#pragma unroll
        for (int q = 0; q < 4; ++q) {
            int c0 = KX + 256 + c8 + 2 * q;
            u32 v0 = (c0 == 4352 || (l >= 0 && c0 == 4353 + l)) ? 0x3F80u : 0u;
            int c1 = c0 + 1;
            u32 v1 = (c1 == 4352 || (l >= 0 && c1 == 4353 + l)) ? 0x3F80u : 0u;
            w[q] = v0 | (v1 << 16);
        }
        *(uint4*)(Abf + (size_t)t * K2 + KX + 256 + c8) = *(uint4*)w;
    }
}

// ---------------- main GEMM: 256x256 tile, balanced 8-phase schedule ----------------
// 8 waves (2M x 4N), BK=64, 128 KiB LDS, reads spread just-in-time per phase
// ({12,8,4,0} ds_read_b128), one 2-load stage per phase, vmcnt(4) at ph4/ph8.

#define SBAR() __builtin_amdgcn_sched_barrier(0)
#define HWBAR() __builtin_amdgcn_s_barrier()
#define PHASE_BAR() do { SBAR(); HWBAR(); SBAR(); } while (0)
#define VMCNT4() asm volatile("s_waitcnt vmcnt(4)" ::: "memory")
#define VMCNT0() asm volatile("s_waitcnt vmcnt(0)" ::: "memory")

#define STAGE(ptr, h, buf, seg, kt)                                                   \
  do { if ((kt) < NKT) {                                                              \
    __builtin_amdgcn_global_load_lds(                                                 \
      (const __attribute__((address_space(1))) u32*)((ptr) + (size_t)((h)*128 + 0)*K2 + (size_t)(kt)*64),  \
      (__attribute__((address_space(3))) u32*)(lds16 + ((((buf)*4+(seg))<<13) + tid*8)), 16, 0, 0);        \
    __builtin_amdgcn_global_load_lds(                                                 \
      (const __attribute__((address_space(1))) u32*)((ptr) + (size_t)((h)*128 + 64)*K2 + (size_t)(kt)*64), \
      (__attribute__((address_space(3))) u32*)(lds16 + ((((buf)*4+(seg))<<13) + tid*8 + 4096)), 16, 0, 0); \
  } } while (0)

// read one m-half of A (4 frags x 2 k-chunks = 8 ds_read_b128)
#define RD_AH(buf, mh, aa)                                                            \
  { _Pragma("unroll") for (int mm = 0; mm < 4; ++mm)                                  \
    _Pragma("unroll") for (int kk = 0; kk < 2; ++kk)                                  \
      aa[mm][kk] = *(const bf16x8*)(smem + (((buf)*4 + wr) << 14) + lrow*128          \
          + (mh)*8192 + mm*2048 + kxb[kk]); }

// read one n-half of B (2 frags x 2 k-chunks = 4 ds_read_b128)
#define RD_BH(buf, nh, bf)                                                            \
  { _Pragma("unroll") for (int nn = 0; nn < 2; ++nn)                                  \
    _Pragma("unroll") for (int kk = 0; kk < 2; ++kk)                                  \
      bf[nn][kk] = *(const bf16x8*)(smem + (((buf)*4 + 2 + (wc>>1)) << 14)            \
          + ((wc&1)*64 + lrow)*128 + ((nh)*2+nn)*2048 + kxb[kk]); }

#define MMQ(mh, nh, aa, bf)                                                           \
  { __builtin_amdgcn_s_setprio(1);                                                    \
    _Pragma("unroll") for (int mm = 0; mm < 4; ++mm)                                  \
    _Pragma("unroll") for (int nn = 0; nn < 2; ++nn)                                  \
    _Pragma("unroll") for (int kk = 0; kk < 2; ++kk)                                  \
      acc[(mh)*4+mm][(nh)*2+nn] = __builtin_amdgcn_mfma_f32_16x16x32_bf16(            \
          aa[mm][kk], bf[nn][kk], acc[(mh)*4+mm][(nh)*2+nn], 0, 0, 0);                \
    __builtin_amdgcn_s_setprio(0); }

__global__ __launch_bounds__(512, 2) void gemm_kernel(const u16* __restrict__ A,
                                                      const u16* __restrict__ B,
                                                      float* __restrict__ C) {
    __shared__ u16 lds16[65536];                 // 128 KiB
    const char* smem = (const char*)lds16;

    const int tid  = threadIdx.x;
    const int lane = tid & 63, wid = tid >> 6;
    const int wr = wid >> 2, wc = wid & 3;       // 2M x 4N wave grid
    const int lrow = lane & 15;
    const int klo  = (lane >> 4) << 4;
    const int sx   = (lrow & 7) << 4;
    const int kxb[2] = { klo ^ sx, (64 + klo) ^ sx };

    // XCD-aware swizzle: 512 blocks, 512 % 8 == 0 -> bijective
    const int wg  = blockIdx.x;
    const int swz = (wg & 7) * 64 + (wg >> 3);
    const int bm = swz >> 4;                     // 32 row-tiles
    const int bn = swz & 15;                     // 16 col-tiles

    const int r0  = tid >> 3;
    const int sc4 = (tid & 7) ^ (r0 & 7);
    const u16* pA = A + (size_t)(bm * 256 + r0) * K2 + sc4 * 8;
    const u16* pB = B + (size_t)(bn * 256 + r0) * K2 + sc4 * 8;

    f32x4 acc[8][4];
#pragma unroll
    for (int m = 0; m < 8; ++m)
#pragma unroll
        for (int n = 0; n < 4; ++n) { f32x4 z = {0.f,0.f,0.f,0.f}; acc[m][n] = z; }
    bf16x8 a0[4][2], a1[4][2], bA[2][2], bB[2][2];

    // prologue: K0 all 4 segs (buf0) + K1 A segs (buf1); K1 B staged ph1/ph2
    STAGE(pA, 0, 0, 0, 0); STAGE(pA, 1, 0, 1, 0);
    STAGE(pB, 0, 0, 2, 0); STAGE(pB, 1, 0, 3, 0);
    STAGE(pA, 0, 1, 0, 1); STAGE(pA, 1, 1, 1, 1);
    VMCNT4();                                    // 12 out -> K0's 8 landed
    PHASE_BAR();

    for (int i = 0; i < GITERS; ++i) {
        const int k1 = 2 * i + 1, kn = 2 * i + 2, kn1 = 2 * i + 3;
        // ph1: K(2i) (mh0,nh0); stage K(2i+1).B0 -> b1 (b1.B last read prev ph7)
        RD_AH(0, 0, a0); RD_BH(0, 0, bA);
        STAGE(pB, 0, 1, 2, k1);
        PHASE_BAR();
        MMQ(0, 0, a0, bA);
        PHASE_BAR();
        // ph2: (mh1,nh0); stage K(2i+1).B1 -> b1
        RD_AH(0, 1, a1);
        STAGE(pB, 1, 1, 3, k1);
        PHASE_BAR();
        MMQ(1, 0, a1, bA);
        PHASE_BAR();
        // ph3: (mh0,nh1); stage K(2i+2).A0 -> b0 (b0.A fully read in ph2)
        RD_BH(0, 1, bB);
        STAGE(pA, 0, 0, 0, kn);
        PHASE_BAR();
        MMQ(0, 1, a0, bB);
        PHASE_BAR();
        // ph4: (mh1,nh1); stage K(2i+2).A1 -> b0; guard K(2i+1) landed
        STAGE(pA, 1, 0, 1, kn);
        PHASE_BAR();
        MMQ(1, 1, a1, bB);
        VMCNT4();
        PHASE_BAR();
        // ph5: K(2i+1) (mh0,nh0); stage K(2i+2).B0 -> b0 (b0.B fully read in ph3)
        RD_AH(1, 0, a0); RD_BH(1, 0, bA);
        STAGE(pB, 0, 0, 2, kn);
        PHASE_BAR();
        MMQ(0, 0, a0, bA);
        PHASE_BAR();
        // ph6: (mh1,nh0); stage K(2i+2).B1 -> b0
        RD_AH(1, 1, a1);
        STAGE(pB, 1, 0, 3, kn);
        PHASE_BAR();
        MMQ(1, 0, a1, bA);
        PHASE_BAR();
        // ph7: (mh0,nh1); stage K(2i+3).A0 -> b1 (b1.A fully read in ph6)
        RD_BH(1, 1, bB);
        STAGE(pA, 0, 1, 0, kn1);
        PHASE_BAR();
        MMQ(0, 1, a0, bB);
        PHASE_BAR();
        // ph8: (mh1,nh1); stage K(2i+3).A1 -> b1; guard K(2i+2) landed
        STAGE(pA, 1, 1, 1, kn1);
        PHASE_BAR();
        MMQ(1, 1, a1, bB);
        VMCNT4();
        PHASE_BAR();
    }

    // tail: K-tile 68 (buf0), staged during iter 33 ph3-6
    VMCNT0();
    PHASE_BAR();
    RD_AH(0, 0, a0); RD_AH(0, 1, a1); RD_BH(0, 0, bA); RD_BH(0, 1, bB);
    MMQ(0, 0, a0, bA); MMQ(1, 0, a1, bA); MMQ(0, 1, a0, bB); MMQ(1, 1, a1, bB);

    // epilogue: C/D layout col = lane&15, row = (lane>>4)*4 + reg
    const int crow0 = bm * 256 + wr * 128 + ((lane >> 4) << 2);
    const int ccol0 = bn * 256 + wc * 64 + (lane & 15);
#pragma unroll
    for (int m = 0; m < 8; ++m)
#pragma unroll
        for (int n = 0; n < 4; ++n)
#pragma unroll
            for (int rg = 0; rg < 4; ++rg)
                C[(size_t)(crow0 + m * 16 + rg) * DOUT + ccol0 + n * 16] = acc[m][n][rg];
}

// ---------------- launch ----------------

extern "C" void kernel_launch(void* const* d_in, const int* in_sizes, int n_in,
                              void* d_out, int out_size, void* d_ws, size_t ws_size,
                              hipStream_t stream) {
    const float* x         = (const float*)d_in[0];
    const float* W         = (const float*)d_in[1];
    const float* base_bias = (const float*)d_in[2];
    const float* lora_a    = (const float*)d_in[3];
    const float* lora_b    = (const float*)d_in[4];
    const float* bias_st   = (const float*)d_in[5];
    const int*   indices   = (const int*)d_in[6];
    float* out = (float*)d_out;

    u16* Abf  = (u16*)d_ws;                         // [T_TOK][K2] bf16
    u16* Bbf  = Abf + (size_t)T_TOK * K2;           // [DOUT][K2] bf16
    u16* Aabf = Bbf + (size_t)DOUT * K2;            // [256][DIN] bf16 lora_a

    pack_mats<<<6144, 256, 0, stream>>>(x, W, Abf, Bbf);
    pack_small<<<1536, 256, 0, stream>>>(lora_b, base_bias, bias_st, lora_a, Bbf, Aabf);
    zfill_kernel<<<256, 512, 0, stream>>>(Abf, Aabf, indices, Abf);
    gemm_kernel<<<512, 512, 0, stream>>>(Abf, Bbf, out);
    (void)in_sizes; (void)n_in; (void)out_size; (void)ws_size;
}